// Round 1
// baseline (346.646 us; speedup 1.0000x reference)
//
#include <hip/hip_runtime.h>

#define NN 100000
#define NE 1600000

typedef unsigned int u32;
typedef unsigned short u16;

// unpack 2 bf16 (packed in a u32) -> float2
__device__ __forceinline__ float2 bf2(u32 v) {
    return make_float2(__uint_as_float(v << 16), __uint_as_float(v & 0xffff0000u));
}
// fp32 -> bf16 with round-to-nearest-even
__device__ __forceinline__ u16 f2bf(float f) {
    u32 u = __float_as_uint(f);
    return (u16)((u + 0x7fffu + ((u >> 16) & 1u)) >> 16);
}

__global__ __launch_bounds__(256) void k_init(int* ecnt, int* counter) {
    int i = blockIdx.x * 256 + threadIdx.x;
    if (i < NN) ecnt[i] = 0;
    if (i == 0) *counter = 0;
}

__global__ __launch_bounds__(256) void k_count(const int* __restrict__ dst, int* __restrict__ ecnt) {
    int e = blockIdx.x * 256 + threadIdx.x;
    if (e < NE) atomicAdd(&ecnt[dst[e]], 1);
}

__global__ __launch_bounds__(256) void k_alloc(const int* __restrict__ ecnt, int* __restrict__ start,
                                               int* __restrict__ cursor, float* __restrict__ dis,
                                               int* __restrict__ counter) {
    int i = blockIdx.x * 256 + threadIdx.x;
    if (i < NN) {
        int c = ecnt[i];
        int s = atomicAdd(counter, (c + 3) & ~3);   // pad segments to 4 for int4 loads
        start[i] = s;
        cursor[i] = s;
        dis[i] = rsqrtf((float)(c + 1));            // +1 = self loop
    }
}

__global__ __launch_bounds__(256) void k_fill(const int* __restrict__ src, const int* __restrict__ dst,
                                              int* __restrict__ cursor, int* __restrict__ col) {
    int e = blockIdx.x * 256 + threadIdx.x;
    if (e < NE) {
        int d = dst[e];
        int p = atomicAdd(&cursor[d], 1);
        col[p] = src[e];
    }
}

// g[i][c] = bf16( dis[i] * sum_k x[i][k] * W[k][c] )   (fp32 accumulate on VALU)
__global__ __launch_bounds__(256) void k_gemm(const float* __restrict__ x, const float* __restrict__ W,
                                              const float* __restrict__ dis, u32* __restrict__ g) {
    __shared__ float xs[64][128];
    int t = threadIdx.x;
    int r0 = blockIdx.x * 64;
    // stage 64 rows of x into LDS (coalesced float4)
    {
        int c = t & 31, rb = t >> 5;
        const float4* x4 = (const float4*)x;
#pragma unroll
        for (int p = 0; p < 8; ++p) {
            int r = rb + p * 8;
            int gr = r0 + r;
            float4 v = (gr < NN) ? x4[(size_t)gr * 32 + c] : make_float4(0.f, 0.f, 0.f, 0.f);
            *(float4*)&xs[r][c * 4] = v;
        }
    }
    __syncthreads();

    int c0 = (t & 31) * 4;       // 4 output cols per thread
    int rg = (t >> 5) * 8;       // 8 rows per thread
    float4 acc[8];
#pragma unroll
    for (int r = 0; r < 8; ++r) acc[r] = make_float4(0.f, 0.f, 0.f, 0.f);

    const float4* W4 = (const float4*)W;
    int cw = c0 >> 2;
    for (int k = 0; k < 128; k += 4) {
        float4 w0 = W4[(k + 0) * 32 + cw];
        float4 w1 = W4[(k + 1) * 32 + cw];
        float4 w2 = W4[(k + 2) * 32 + cw];
        float4 w3 = W4[(k + 3) * 32 + cw];
#pragma unroll
        for (int r = 0; r < 8; ++r) {
            float4 xv = *(const float4*)&xs[rg + r][k];
            acc[r].x = fmaf(xv.x, w0.x, fmaf(xv.y, w1.x, fmaf(xv.z, w2.x, fmaf(xv.w, w3.x, acc[r].x))));
            acc[r].y = fmaf(xv.x, w0.y, fmaf(xv.y, w1.y, fmaf(xv.z, w2.y, fmaf(xv.w, w3.y, acc[r].y))));
            acc[r].z = fmaf(xv.x, w0.z, fmaf(xv.y, w1.z, fmaf(xv.z, w2.z, fmaf(xv.w, w3.z, acc[r].z))));
            acc[r].w = fmaf(xv.x, w0.w, fmaf(xv.y, w1.w, fmaf(xv.z, w2.w, fmaf(xv.w, w3.w, acc[r].w))));
        }
    }

#pragma unroll
    for (int r = 0; r < 8; ++r) {
        int gr = r0 + rg + r;
        if (gr < NN) {
            float d = dis[gr];
            u32 lo = (u32)f2bf(acc[r].x * d) | ((u32)f2bf(acc[r].y * d) << 16);
            u32 hi = (u32)f2bf(acc[r].z * d) | ((u32)f2bf(acc[r].w * d) << 16);
            *(uint2*)&g[(size_t)gr * 64 + (c0 >> 1)] = make_uint2(lo, hi);
        }
    }
}

// out[i] = relu( dis[i] * (g[i] + sum_{src->i} g[src]) + b )   ; one wave per node
__global__ __launch_bounds__(256) void k_aggr(const u32* __restrict__ g, const int* __restrict__ col,
                                              const int* __restrict__ start, const int* __restrict__ ecnt,
                                              const float* __restrict__ dis, const float* __restrict__ b,
                                              float* __restrict__ out) {
    int wid = (blockIdx.x * 256 + threadIdx.x) >> 6;
    int lane = threadIdx.x & 63;
    if (wid >= NN) return;
    int s = start[wid], cnt = ecnt[wid];

    float2 acc = bf2(g[(size_t)wid * 64 + lane]);   // self-loop term
    int e = 0;
    for (; e + 4 <= cnt; e += 4) {
        int4 ss = *(const int4*)&col[s + e];        // s and e are 4-aligned
        float2 a0 = bf2(g[(size_t)ss.x * 64 + lane]);
        float2 a1 = bf2(g[(size_t)ss.y * 64 + lane]);
        float2 a2 = bf2(g[(size_t)ss.z * 64 + lane]);
        float2 a3 = bf2(g[(size_t)ss.w * 64 + lane]);
        acc.x += (a0.x + a1.x) + (a2.x + a3.x);
        acc.y += (a0.y + a1.y) + (a2.y + a3.y);
    }
    for (; e < cnt; ++e) {
        int sc = col[s + e];
        float2 a = bf2(g[(size_t)sc * 64 + lane]);
        acc.x += a.x;
        acc.y += a.y;
    }

    float di = dis[wid];
    float2 bb = *(const float2*)&b[lane * 2];
    float2 o;
    o.x = fmaxf(fmaf(di, acc.x, bb.x), 0.f);
    o.y = fmaxf(fmaf(di, acc.y, bb.y), 0.f);
    ((float2*)out)[(size_t)wid * 64 + lane] = o;
}

extern "C" void kernel_launch(void* const* d_in, const int* in_sizes, int n_in,
                              void* d_out, int out_size, void* d_ws, size_t ws_size,
                              hipStream_t stream) {
    const float* x = (const float*)d_in[0];
    const int* ei = (const int*)d_in[1];
    const float* W = (const float*)d_in[2];
    const float* b = (const float*)d_in[3];
    float* out = (float*)d_out;
    const int* srcA = ei;        // edge_index[0] = message sources
    const int* dstA = ei + NE;   // edge_index[1] = aggregation targets

    char* ws = (char*)d_ws;
    size_t off = 0;
    auto take = [&](size_t bytes) -> char* {
        char* p = ws + off;
        off = (off + bytes + 255) & ~(size_t)255;
        return p;
    };
    u32*   g       = (u32*)  take((size_t)NN * 128 * 2);          // bf16 scaled features, 25.6 MB
    float* dis     = (float*)take((size_t)NN * 4);
    int*   ecnt    = (int*)  take((size_t)NN * 4);
    int*   startA  = (int*)  take((size_t)NN * 4);
    int*   cursor  = (int*)  take((size_t)NN * 4);
    int*   colA    = (int*)  take(((size_t)NE + 3 * (size_t)NN + 256) * 4);  // padded CSR cols
    int*   counter = (int*)  take(256);

    k_init <<<(NN + 255) / 256, 256, 0, stream>>>(ecnt, counter);
    k_count<<<(NE + 255) / 256, 256, 0, stream>>>(dstA, ecnt);
    k_alloc<<<(NN + 255) / 256, 256, 0, stream>>>(ecnt, startA, cursor, dis, counter);
    k_fill <<<(NE + 255) / 256, 256, 0, stream>>>(srcA, dstA, cursor, colA);
    k_gemm <<<(NN + 63) / 64, 256, 0, stream>>>(x, W, dis, g);
    k_aggr <<<NN / 4, 256, 0, stream>>>(g, colA, startA, ecnt, dis, b, out);
}

// Round 2
// 178.237 us; speedup vs baseline: 1.9449x; 1.9449x over previous
//
#include <hip/hip_runtime.h>

#define NN 100000
#define NE 1600000
#define NB 196            // buckets = ceil(NN / 512)
#define BSH 9             // bucket shift (512 node ids per bucket)
#define CAPB 12288        // staging capacity per bucket (edges); mean 8163, sd 90
#define CAPC 14336        // col capacity per bucket (>= CAPB + 4*512 pad)

typedef unsigned int u32;
typedef unsigned short u16;

// unpack 2 bf16 (packed in a u32) -> float2
__device__ __forceinline__ float2 bf2(u32 v) {
    return make_float2(__uint_as_float(v << 16), __uint_as_float(v & 0xffff0000u));
}
// fp32 -> bf16 with round-to-nearest-even
__device__ __forceinline__ u16 f2bf(float f) {
    u32 u = __float_as_uint(f);
    return (u16)((u + 0x7fffu + ((u >> 16) & 1u)) >> 16);
}

__global__ __launch_bounds__(256) void k_zero(int* gcur) {
    int i = threadIdx.x;
    if (i < NB) gcur[i] = 0;
}

// Pass A: bin edges into 196 coarse buckets by dst>>9, packed (dstLow<<17)|src in u32.
__global__ __launch_bounds__(1024) void k_binA(const int* __restrict__ src, const int* __restrict__ dst,
                                               int* __restrict__ gcur, u32* __restrict__ staging) {
    __shared__ int hist[NB];
    __shared__ int cur[NB];
    int t = threadIdx.x;
    int base = blockIdx.x * 8192;
    for (int i = t; i < NB; i += 1024) hist[i] = 0;
    __syncthreads();
    u32 pk[8];
    int bk[8];
#pragma unroll
    for (int j = 0; j < 8; ++j) {
        int e = base + j * 1024 + t;
        bk[j] = -1;
        if (e < NE) {
            int s = src[e], d = dst[e];
            bk[j] = d >> BSH;
            pk[j] = ((u32)(d & 511) << 17) | (u32)s;
            atomicAdd(&hist[bk[j]], 1);
        }
    }
    __syncthreads();
    for (int i = t; i < NB; i += 1024) {
        int h = hist[i];
        cur[i] = h ? atomicAdd(&gcur[i], h) : 0;   // reserve contiguous chunk per bucket
    }
    __syncthreads();
#pragma unroll
    for (int j = 0; j < 8; ++j) {
        if (bk[j] >= 0) {
            int pos = atomicAdd(&cur[bk[j]], 1);
            if (pos < CAPB) staging[(size_t)bk[j] * CAPB + pos] = pk[j];
        }
    }
}

// Pass B: one block per bucket -> per-node counts, segment alloc, fill col (L2-local window).
__global__ __launch_bounds__(256) void k_passB(const u32* __restrict__ staging, const int* __restrict__ gcur,
                                               int* __restrict__ col, int* __restrict__ startA,
                                               int* __restrict__ ecnt, float* __restrict__ dis) {
    __shared__ int cnt[512];
    __shared__ int loc[512];
    __shared__ int total;
    int b = blockIdx.x, t = threadIdx.x;
    int bcnt = gcur[b];
    if (bcnt > CAPB) bcnt = CAPB;
    for (int i = t; i < 512; i += 256) cnt[i] = 0;
    if (t == 0) total = 0;
    __syncthreads();
    const u32* st = staging + (size_t)b * CAPB;
    for (int i = t; i < bcnt; i += 256) atomicAdd(&cnt[st[i] >> 17], 1);
    __syncthreads();
    for (int i = t; i < 512; i += 256) {
        int c = cnt[i];
        loc[i] = atomicAdd(&total, (c + 3) & ~3);   // pad segments to 4 for int4 loads
    }
    __syncthreads();
    int cbase = b * CAPC;
    for (int i = t; i < 512; i += 256) {
        int node = (b << BSH) + i;
        if (node < NN) {
            startA[node] = cbase + loc[i];
            ecnt[node]   = cnt[i];
            dis[node]    = rsqrtf((float)cnt[i] + 1.0f);   // +1 = self loop
        }
    }
    __syncthreads();
    for (int i = t; i < 512; i += 256) cnt[i] = loc[i];    // reuse cnt as fill cursor
    __syncthreads();
    for (int i = t; i < bcnt; i += 256) {
        u32 p = st[i];
        int pos = atomicAdd(&cnt[p >> 17], 1);
        col[cbase + pos] = (int)(p & 0x1ffffu);
    }
}

// g[i][c] = bf16( dis[i] * sum_k x[i][k] * W[k][c] )   (fp32 accumulate on VALU)
__global__ __launch_bounds__(256) void k_gemm(const float* __restrict__ x, const float* __restrict__ W,
                                              const float* __restrict__ dis, u32* __restrict__ g) {
    __shared__ float xs[64][128];
    int t = threadIdx.x;
    int r0 = blockIdx.x * 64;
    {
        int c = t & 31, rb = t >> 5;
        const float4* x4 = (const float4*)x;
#pragma unroll
        for (int p = 0; p < 8; ++p) {
            int r = rb + p * 8;
            int gr = r0 + r;
            float4 v = (gr < NN) ? x4[(size_t)gr * 32 + c] : make_float4(0.f, 0.f, 0.f, 0.f);
            *(float4*)&xs[r][c * 4] = v;
        }
    }
    __syncthreads();

    int c0 = (t & 31) * 4;
    int rg = (t >> 5) * 8;
    float4 acc[8];
#pragma unroll
    for (int r = 0; r < 8; ++r) acc[r] = make_float4(0.f, 0.f, 0.f, 0.f);

    const float4* W4 = (const float4*)W;
    int cw = c0 >> 2;
    for (int k = 0; k < 128; k += 4) {
        float4 w0 = W4[(k + 0) * 32 + cw];
        float4 w1 = W4[(k + 1) * 32 + cw];
        float4 w2 = W4[(k + 2) * 32 + cw];
        float4 w3 = W4[(k + 3) * 32 + cw];
#pragma unroll
        for (int r = 0; r < 8; ++r) {
            float4 xv = *(const float4*)&xs[rg + r][k];
            acc[r].x = fmaf(xv.x, w0.x, fmaf(xv.y, w1.x, fmaf(xv.z, w2.x, fmaf(xv.w, w3.x, acc[r].x))));
            acc[r].y = fmaf(xv.x, w0.y, fmaf(xv.y, w1.y, fmaf(xv.z, w2.y, fmaf(xv.w, w3.y, acc[r].y))));
            acc[r].z = fmaf(xv.x, w0.z, fmaf(xv.y, w1.z, fmaf(xv.z, w2.z, fmaf(xv.w, w3.z, acc[r].z))));
            acc[r].w = fmaf(xv.x, w0.w, fmaf(xv.y, w1.w, fmaf(xv.z, w2.w, fmaf(xv.w, w3.w, acc[r].w))));
        }
    }

#pragma unroll
    for (int r = 0; r < 8; ++r) {
        int gr = r0 + rg + r;
        if (gr < NN) {
            float d = dis[gr];
            u32 lo = (u32)f2bf(acc[r].x * d) | ((u32)f2bf(acc[r].y * d) << 16);
            u32 hi = (u32)f2bf(acc[r].z * d) | ((u32)f2bf(acc[r].w * d) << 16);
            *(uint2*)&g[(size_t)gr * 64 + (c0 >> 1)] = make_uint2(lo, hi);
        }
    }
}

// out[i] = relu( dis[i] * (g[i] + sum_{src->i} g[src]) + b )   ; one wave per node
__global__ __launch_bounds__(256) void k_aggr(const u32* __restrict__ g, const int* __restrict__ col,
                                              const int* __restrict__ start, const int* __restrict__ ecnt,
                                              const float* __restrict__ dis, const float* __restrict__ b,
                                              float* __restrict__ out) {
    int wid = (blockIdx.x * 256 + threadIdx.x) >> 6;
    int lane = threadIdx.x & 63;
    if (wid >= NN) return;
    int s = start[wid], cnt = ecnt[wid];

    float2 acc = bf2(g[(size_t)wid * 64 + lane]);   // self-loop term
    int e = 0;
    for (; e + 4 <= cnt; e += 4) {
        int4 ss = *(const int4*)&col[s + e];
        float2 a0 = bf2(g[(size_t)ss.x * 64 + lane]);
        float2 a1 = bf2(g[(size_t)ss.y * 64 + lane]);
        float2 a2 = bf2(g[(size_t)ss.z * 64 + lane]);
        float2 a3 = bf2(g[(size_t)ss.w * 64 + lane]);
        acc.x += (a0.x + a1.x) + (a2.x + a3.x);
        acc.y += (a0.y + a1.y) + (a2.y + a3.y);
    }
    for (; e < cnt; ++e) {
        int sc = col[s + e];
        float2 a = bf2(g[(size_t)sc * 64 + lane]);
        acc.x += a.x;
        acc.y += a.y;
    }

    float di = dis[wid];
    float2 bb = *(const float2*)&b[lane * 2];
    float2 o;
    o.x = fmaxf(fmaf(di, acc.x, bb.x), 0.f);
    o.y = fmaxf(fmaf(di, acc.y, bb.y), 0.f);
    ((float2*)out)[(size_t)wid * 64 + lane] = o;
}

extern "C" void kernel_launch(void* const* d_in, const int* in_sizes, int n_in,
                              void* d_out, int out_size, void* d_ws, size_t ws_size,
                              hipStream_t stream) {
    const float* x = (const float*)d_in[0];
    const int* ei = (const int*)d_in[1];
    const float* W = (const float*)d_in[2];
    const float* b = (const float*)d_in[3];
    float* out = (float*)d_out;
    const int* srcA = ei;        // edge_index[0] = message sources
    const int* dstA = ei + NE;   // edge_index[1] = aggregation targets

    char* ws = (char*)d_ws;
    size_t off = 0;
    auto take = [&](size_t bytes) -> char* {
        char* p = ws + off;
        off = (off + bytes + 255) & ~(size_t)255;
        return p;
    };
    u32*   g      = (u32*)  take((size_t)NN * 128 * 2);        // bf16 scaled features, 25.6 MB
    float* dis    = (float*)take((size_t)NN * 4);
    int*   ecnt   = (int*)  take((size_t)NN * 4);
    int*   startA = (int*)  take((size_t)NN * 4);
    int*   colA   = (int*)  take((size_t)NB * CAPC * 4);       // bucketed CSR cols, 11.2 MB
    int*   gcur   = (int*)  take(256 * 4);

    u32* staging = g;   // staging (9.6 MB) aliases g: g is written only later by k_gemm

    k_zero <<<1, 256, 0, stream>>>(gcur);
    k_binA <<<(NE + 8191) / 8192, 1024, 0, stream>>>(srcA, dstA, gcur, staging);
    k_passB<<<NB, 256, 0, stream>>>(staging, gcur, colA, startA, ecnt, dis);
    k_gemm <<<(NN + 63) / 64, 256, 0, stream>>>(x, W, dis, g);
    k_aggr <<<NN / 4, 256, 0, stream>>>(g, colA, startA, ecnt, dis, b, out);
}

// Round 3
// 144.818 us; speedup vs baseline: 2.3937x; 1.2308x over previous
//
#include <hip/hip_runtime.h>

#define NN 100000
#define NE 1600000
#define NB 196            // buckets = ceil(NN / 512)
#define BSH 9             // bucket shift (512 node ids per bucket)
#define CAPB 12288        // staging capacity per bucket (edges); mean 8163, sd 90
#define CAPC 14336        // col capacity per bucket (>= CAPB + 4*512 pad)

typedef unsigned int u32;
typedef unsigned short u16;
typedef short short8 __attribute__((ext_vector_type(8)));
typedef float floatx4 __attribute__((ext_vector_type(4)));

__device__ __forceinline__ float bf2f(u16 h) { return __uint_as_float((u32)h << 16); }
__device__ __forceinline__ u16 f2bf(float f) {
    u32 u = __float_as_uint(f);
    return (u16)((u + 0x7fffu + ((u >> 16) & 1u)) >> 16);
}
// unpack 2 bf16 (packed in a u32) -> float2
__device__ __forceinline__ float2 bf2(u32 v) {
    return make_float2(__uint_as_float(v << 16), __uint_as_float(v & 0xffff0000u));
}

__global__ __launch_bounds__(256) void k_zero(int* gcur) {
    int i = threadIdx.x;
    if (i < NB) gcur[i] = 0;
}

// Transpose W -> Wt[n][k] bf16, PRE-SWIZZLED in global (m173 pattern): byte ^= (n&7)<<4.
__global__ __launch_bounds__(256) void k_prepW(const float* __restrict__ W, u16* __restrict__ wtb) {
    int t = blockIdx.x * 256 + threadIdx.x;
    if (t >= 128 * 128) return;
    int n = t >> 7, k = t & 127;
    float v = W[k * 128 + n];
    u32 byteoff = (u32)n * 256 + (((u32)k * 2) ^ (u32)((n & 7) << 4));
    wtb[byteoff >> 1] = f2bf(v);
}

// Pass A: bin edges into 196 coarse buckets by dst>>9, packed (dstLow<<17)|src in u32.
__global__ __launch_bounds__(1024) void k_binA(const int* __restrict__ src, const int* __restrict__ dst,
                                               int* __restrict__ gcur, u32* __restrict__ staging) {
    __shared__ int hist[NB];
    __shared__ int cur[NB];
    int t = threadIdx.x;
    int base = blockIdx.x * 8192;
    for (int i = t; i < NB; i += 1024) hist[i] = 0;
    __syncthreads();
    u32 pk[8];
    int bk[8];
#pragma unroll
    for (int j = 0; j < 8; ++j) {
        int e = base + j * 1024 + t;
        bk[j] = -1;
        if (e < NE) {
            int s = src[e], d = dst[e];
            bk[j] = d >> BSH;
            pk[j] = ((u32)(d & 511) << 17) | (u32)s;
            atomicAdd(&hist[bk[j]], 1);
        }
    }
    __syncthreads();
    for (int i = t; i < NB; i += 1024) {
        int h = hist[i];
        cur[i] = h ? atomicAdd(&gcur[i], h) : 0;
    }
    __syncthreads();
#pragma unroll
    for (int j = 0; j < 8; ++j) {
        if (bk[j] >= 0) {
            int pos = atomicAdd(&cur[bk[j]], 1);
            if (pos < CAPB) staging[(size_t)bk[j] * CAPB + pos] = pk[j];
        }
    }
}

// Pass B: one block per bucket -> per-node counts, segment alloc, fill col (L2-local window).
__global__ __launch_bounds__(256) void k_passB(const u32* __restrict__ staging, const int* __restrict__ gcur,
                                               int* __restrict__ col, int* __restrict__ startA,
                                               int* __restrict__ ecnt, float* __restrict__ dis) {
    __shared__ int cnt[512];
    __shared__ int loc[512];
    __shared__ int total;
    int b = blockIdx.x, t = threadIdx.x;
    int bcnt = gcur[b];
    if (bcnt > CAPB) bcnt = CAPB;
    for (int i = t; i < 512; i += 256) cnt[i] = 0;
    if (t == 0) total = 0;
    __syncthreads();
    const u32* st = staging + (size_t)b * CAPB;
    for (int i = t; i < bcnt; i += 256) atomicAdd(&cnt[st[i] >> 17], 1);
    __syncthreads();
    for (int i = t; i < 512; i += 256) {
        int c = cnt[i];
        loc[i] = atomicAdd(&total, (c + 3) & ~3);
    }
    __syncthreads();
    int cbase = b * CAPC;
    for (int i = t; i < 512; i += 256) {
        int node = (b << BSH) + i;
        if (node < NN) {
            startA[node] = cbase + loc[i];
            ecnt[node]   = cnt[i];
            dis[node]    = rsqrtf((float)cnt[i] + 1.0f);
        }
    }
    __syncthreads();
    for (int i = t; i < 512; i += 256) cnt[i] = loc[i];
    __syncthreads();
    for (int i = t; i < bcnt; i += 256) {
        u32 p = st[i];
        int pos = atomicAdd(&cnt[p >> 17], 1);
        col[cbase + pos] = (int)(p & 0x1ffffu);
    }
}

// MFMA GEMM: g[i][c] = bf16( dis[i] * sum_k x[i][k]*W[k][c] ), x split to bf16 hi+lo.
__global__ __launch_bounds__(256) void k_gemm(const float* __restrict__ x, const u16* __restrict__ wtb,
                                              const float* __restrict__ dis, u16* __restrict__ g) {
    __shared__ char smem[65536];
    char* xh = smem;             // [64][128] bf16, swizzled, 16KB
    char* xl = smem + 16384;     // 16KB
    char* wt = smem + 32768;     // [128][128] bf16 (n-major), swizzled, 32KB
    int t = threadIdx.x;
    int r0 = blockIdx.x * 64;

    // copy pre-swizzled Wt (32KB) linearly
    {
        const float4* s4 = (const float4*)wtb;
        float4* d4 = (float4*)wt;
#pragma unroll
        for (int i = 0; i < 8; ++i) d4[t + i * 256] = s4[t + i * 256];
    }
    // stage x -> bf16 hi/lo, swizzled: byte ^= (row&7)<<4
    {
        const float4* x4 = (const float4*)x;
        int c4 = t & 31, rb = t >> 5;
#pragma unroll
        for (int p = 0; p < 8; ++p) {
            int r = rb + p * 8;
            int gr = r0 + r;
            float4 v = (gr < NN) ? x4[(size_t)gr * 32 + c4] : make_float4(0.f, 0.f, 0.f, 0.f);
            u16 h0 = f2bf(v.x), h1 = f2bf(v.y), h2 = f2bf(v.z), h3 = f2bf(v.w);
            u16 q0 = f2bf(v.x - bf2f(h0)), q1 = f2bf(v.y - bf2f(h1));
            u16 q2 = f2bf(v.z - bf2f(h2)), q3 = f2bf(v.w - bf2f(h3));
            u32 off = (u32)r * 256 + (((u32)c4 * 8) ^ (u32)((r & 7) << 4));
            *(uint2*)(xh + off) = make_uint2((u32)h0 | ((u32)h1 << 16), (u32)h2 | ((u32)h3 << 16));
            *(uint2*)(xl + off) = make_uint2((u32)q0 | ((u32)q1 << 16), (u32)q2 | ((u32)q3 << 16));
        }
    }
    __syncthreads();

    int w = t >> 6, l = t & 63;
    int lr = l & 15;          // row-in-tile for A, col-in-tile for B
    int hi2 = l >> 4;         // k-chunk-of-8 selector
    int arow = w * 16 + lr;
    u32 aswz = (u32)((arow & 7) << 4);
    floatx4 acc[8];
#pragma unroll
    for (int nt = 0; nt < 8; ++nt) acc[nt] = (floatx4){0.f, 0.f, 0.f, 0.f};

#pragma unroll
    for (int kc = 0; kc < 4; ++kc) {
        u32 akoff = (u32)(kc * 64 + hi2 * 16);
        short8 ah = *(short8*)(xh + (u32)arow * 256 + (akoff ^ aswz));
        short8 al = *(short8*)(xl + (u32)arow * 256 + (akoff ^ aswz));
#pragma unroll
        for (int nt = 0; nt < 8; ++nt) {
            int brow = nt * 16 + lr;
            short8 bv = *(short8*)(wt + (u32)brow * 256 + (akoff ^ (u32)((brow & 7) << 4)));
            acc[nt] = __builtin_amdgcn_mfma_f32_16x16x32_bf16(ah, bv, acc[nt], 0, 0, 0);
            acc[nt] = __builtin_amdgcn_mfma_f32_16x16x32_bf16(al, bv, acc[nt], 0, 0, 0);
        }
    }

    // epilogue: D mapping col=lane&15, row=(lane>>4)*4+reg (m89)
    int rbase = r0 + w * 16 + hi2 * 4;
#pragma unroll
    for (int q = 0; q < 4; ++q) {
        int grow = rbase + q;
        if (grow < NN) {
            float d = dis[grow];
#pragma unroll
            for (int nt = 0; nt < 8; ++nt) {
                g[(size_t)grow * 128 + nt * 16 + lr] = f2bf(d * acc[nt][q]);
            }
        }
    }
}

// out[i] = relu( dis[i]*(g[i] + sum g[src]) + b ) ; 2 nodes per wave, 32 lanes each.
__global__ __launch_bounds__(256) void k_aggr(const u32* __restrict__ g, const int* __restrict__ col,
                                              const int* __restrict__ start, const int* __restrict__ ecnt,
                                              const float* __restrict__ dis, const float* __restrict__ b,
                                              float* __restrict__ out) {
    int wv = (blockIdx.x * 256 + threadIdx.x) >> 6;
    int l = threadIdx.x & 63;
    int node = wv * 2 + (l >> 5);
    int sl = l & 31;
    if (node >= NN) return;
    const uint2* g2 = (const uint2*)g;
    int s = start[node], cnt = ecnt[node];

    uint2 sv = g2[(size_t)node * 32 + sl];    // self-loop term
    float2 p0 = bf2(sv.x), p1 = bf2(sv.y);
    float4 acc = make_float4(p0.x, p0.y, p1.x, p1.y);

    int e = 0;
    for (; e + 4 <= cnt; e += 4) {
        int4 ss = *(const int4*)&col[s + e];
        uint2 a0 = g2[(size_t)ss.x * 32 + sl];
        uint2 a1 = g2[(size_t)ss.y * 32 + sl];
        uint2 a2 = g2[(size_t)ss.z * 32 + sl];
        uint2 a3 = g2[(size_t)ss.w * 32 + sl];
        float2 u0 = bf2(a0.x), v0 = bf2(a0.y), u1 = bf2(a1.x), v1 = bf2(a1.y);
        float2 u2 = bf2(a2.x), v2 = bf2(a2.y), u3 = bf2(a3.x), v3 = bf2(a3.y);
        acc.x += (u0.x + u1.x) + (u2.x + u3.x);
        acc.y += (u0.y + u1.y) + (u2.y + u3.y);
        acc.z += (v0.x + v1.x) + (v2.x + v3.x);
        acc.w += (v0.y + v1.y) + (v2.y + v3.y);
    }
    for (; e < cnt; ++e) {
        int sc = col[s + e];
        uint2 a = g2[(size_t)sc * 32 + sl];
        float2 u = bf2(a.x), v = bf2(a.y);
        acc.x += u.x; acc.y += u.y; acc.z += v.x; acc.w += v.y;
    }

    float di = dis[node];
    float4 bb = *(const float4*)&b[sl * 4];
    float4 o;
    o.x = fmaxf(fmaf(di, acc.x, bb.x), 0.f);
    o.y = fmaxf(fmaf(di, acc.y, bb.y), 0.f);
    o.z = fmaxf(fmaf(di, acc.z, bb.z), 0.f);
    o.w = fmaxf(fmaf(di, acc.w, bb.w), 0.f);
    *(float4*)&out[(size_t)node * 128 + sl * 4] = o;
}

extern "C" void kernel_launch(void* const* d_in, const int* in_sizes, int n_in,
                              void* d_out, int out_size, void* d_ws, size_t ws_size,
                              hipStream_t stream) {
    const float* x = (const float*)d_in[0];
    const int* ei = (const int*)d_in[1];
    const float* W = (const float*)d_in[2];
    const float* b = (const float*)d_in[3];
    float* out = (float*)d_out;
    const int* srcA = ei;        // edge_index[0] = message sources
    const int* dstA = ei + NE;   // edge_index[1] = aggregation targets

    char* ws = (char*)d_ws;
    size_t off = 0;
    auto take = [&](size_t bytes) -> char* {
        char* p = ws + off;
        off = (off + bytes + 255) & ~(size_t)255;
        return p;
    };
    u16*   g      = (u16*)  take((size_t)NN * 128 * 2);        // bf16 scaled features, 25.6 MB
    float* dis    = (float*)take((size_t)NN * 4);
    int*   ecnt   = (int*)  take((size_t)NN * 4);
    int*   startA = (int*)  take((size_t)NN * 4);
    int*   colA   = (int*)  take((size_t)NB * CAPC * 4);       // bucketed CSR cols, 11.2 MB
    int*   gcur   = (int*)  take(256 * 4);
    u16*   wtb    = (u16*)  take(128 * 128 * 2);               // pre-swizzled Wt bf16, 32KB

    u32* staging = (u32*)g;   // staging (9.6 MB) aliases g: g written only later by k_gemm

    k_prepW<<<64, 256, 0, stream>>>(W, wtb);
    k_zero <<<1, 256, 0, stream>>>(gcur);
    k_binA <<<(NE + 8191) / 8192, 1024, 0, stream>>>(srcA, dstA, gcur, staging);
    k_passB<<<NB, 256, 0, stream>>>(staging, gcur, colA, startA, ecnt, dis);
    k_gemm <<<(NN + 63) / 64, 256, 0, stream>>>(x, wtb, dis, g);
    k_aggr <<<(NN / 2 + 3) / 4, 256, 0, stream>>>((const u32*)g, colA, startA, ecnt, dis, b, out);
}

// Round 5
// 144.129 us; speedup vs baseline: 2.4051x; 1.0048x over previous
//
#include <hip/hip_runtime.h>

#define NN 100000
#define NE 1600000
#define NB 196            // buckets = ceil(NN / 512)
#define BSH 9             // bucket shift (512 node ids per bucket)
#define CAPB 12288        // staging capacity per bucket (edges); mean 8163, sd 90
#define CAPC 14336        // col capacity per bucket (>= CAPB + 4*512 pad)

typedef unsigned int u32;
typedef unsigned short u16;
typedef short short8 __attribute__((ext_vector_type(8)));
typedef float floatx4 __attribute__((ext_vector_type(4)));
typedef int intx4 __attribute__((ext_vector_type(4)));
typedef float fltx4 __attribute__((ext_vector_type(4)));

__device__ __forceinline__ float bf2f(u16 h) { return __uint_as_float((u32)h << 16); }
__device__ __forceinline__ u16 f2bf(float f) {
    u32 u = __float_as_uint(f);
    return (u16)((u + 0x7fffu + ((u >> 16) & 1u)) >> 16);
}
// unpack 2 bf16 (packed in a u32) -> float2
__device__ __forceinline__ float2 bf2(u32 v) {
    return make_float2(__uint_as_float(v << 16), __uint_as_float(v & 0xffff0000u));
}
// accumulate 8 bf16 (uint4) into two float4 accs
__device__ __forceinline__ void acc8(float4& A, float4& B, uint4 a) {
    float2 u0 = bf2(a.x), u1 = bf2(a.y), u2 = bf2(a.z), u3 = bf2(a.w);
    A.x += u0.x; A.y += u0.y; A.z += u1.x; A.w += u1.y;
    B.x += u2.x; B.y += u2.y; B.z += u3.x; B.w += u3.y;
}

// Transpose W -> Wt[n][k] bf16, PRE-SWIZZLED in global (m173): byte ^= (n&7)<<4. Also zeroes gcur.
__global__ __launch_bounds__(256) void k_prepW(const float* __restrict__ W, u16* __restrict__ wtb,
                                               int* __restrict__ gcur) {
    int t = blockIdx.x * 256 + threadIdx.x;
    if (t < NB) gcur[t] = 0;
    if (t >= 128 * 128) return;
    int n = t >> 7, k = t & 127;
    float v = W[k * 128 + n];
    u32 byteoff = (u32)n * 256 + (((u32)k * 2) ^ (u32)((n & 7) << 4));
    wtb[byteoff >> 1] = f2bf(v);
}

// Pass A: bin edges into 196 coarse buckets by dst>>9, packed (dstLow<<17)|src in u32.
__global__ __launch_bounds__(1024) void k_binA(const int* __restrict__ src, const int* __restrict__ dst,
                                               int* __restrict__ gcur, u32* __restrict__ staging) {
    __shared__ int hist[NB];
    __shared__ int cur[NB];
    int t = threadIdx.x;
    int base = blockIdx.x * 8192;
    for (int i = t; i < NB; i += 1024) hist[i] = 0;
    __syncthreads();
    u32 pk[8];
    int bk[8];
#pragma unroll
    for (int j = 0; j < 8; ++j) {
        int e = base + j * 1024 + t;
        bk[j] = -1;
        if (e < NE) {
            int s = src[e], d = dst[e];
            bk[j] = d >> BSH;
            pk[j] = ((u32)(d & 511) << 17) | (u32)s;
            atomicAdd(&hist[bk[j]], 1);
        }
    }
    __syncthreads();
    for (int i = t; i < NB; i += 1024) {
        int h = hist[i];
        cur[i] = h ? atomicAdd(&gcur[i], h) : 0;
    }
    __syncthreads();
#pragma unroll
    for (int j = 0; j < 8; ++j) {
        if (bk[j] >= 0) {
            int pos = atomicAdd(&cur[bk[j]], 1);
            if (pos < CAPB) staging[(size_t)bk[j] * CAPB + pos] = pk[j];
        }
    }
}

// Pass B: one block per bucket -> per-node counts, segment alloc, fill col (L2-local window).
__global__ __launch_bounds__(256) void k_passB(const u32* __restrict__ staging, const int* __restrict__ gcur,
                                               int* __restrict__ col, int* __restrict__ startA,
                                               int* __restrict__ ecnt, float* __restrict__ dis) {
    __shared__ int cnt[512];
    __shared__ int loc[512];
    __shared__ int total;
    int b = blockIdx.x, t = threadIdx.x;
    int bcnt = gcur[b];
    if (bcnt > CAPB) bcnt = CAPB;
    for (int i = t; i < 512; i += 256) cnt[i] = 0;
    if (t == 0) total = 0;
    __syncthreads();
    const u32* st = staging + (size_t)b * CAPB;
    for (int i = t; i < bcnt; i += 256) atomicAdd(&cnt[st[i] >> 17], 1);
    __syncthreads();
    for (int i = t; i < 512; i += 256) {
        int c = cnt[i];
        loc[i] = atomicAdd(&total, (c + 3) & ~3);
    }
    __syncthreads();
    int cbase = b * CAPC;
    for (int i = t; i < 512; i += 256) {
        int node = (b << BSH) + i;
        if (node < NN) {
            startA[node] = cbase + loc[i];
            ecnt[node]   = cnt[i];
            dis[node]    = rsqrtf((float)cnt[i] + 1.0f);
        }
    }
    __syncthreads();
    for (int i = t; i < 512; i += 256) cnt[i] = loc[i];
    __syncthreads();
    for (int i = t; i < bcnt; i += 256) {
        u32 p = st[i];
        int pos = atomicAdd(&cnt[p >> 17], 1);
        col[cbase + pos] = (int)(p & 0x1ffffu);
    }
}

// MFMA GEMM: g[i][c] = bf16( dis[i] * sum_k x[i][k]*W[k][c] ), x split to bf16 hi+lo.
__global__ __launch_bounds__(256) void k_gemm(const float* __restrict__ x, const u16* __restrict__ wtb,
                                              const float* __restrict__ dis, u16* __restrict__ g) {
    __shared__ char smem[65536];
    char* xh = smem;             // [64][128] bf16, swizzled, 16KB
    char* xl = smem + 16384;     // 16KB
    char* wt = smem + 32768;     // [128][128] bf16 (n-major), swizzled, 32KB
    int t = threadIdx.x;
    int r0 = blockIdx.x * 64;

    {
        const float4* s4 = (const float4*)wtb;
        float4* d4 = (float4*)wt;
#pragma unroll
        for (int i = 0; i < 8; ++i) d4[t + i * 256] = s4[t + i * 256];
    }
    {
        const float4* x4 = (const float4*)x;
        int c4 = t & 31, rb = t >> 5;
#pragma unroll
        for (int p = 0; p < 8; ++p) {
            int r = rb + p * 8;
            int gr = r0 + r;
            float4 v = (gr < NN) ? x4[(size_t)gr * 32 + c4] : make_float4(0.f, 0.f, 0.f, 0.f);
            u16 h0 = f2bf(v.x), h1 = f2bf(v.y), h2 = f2bf(v.z), h3 = f2bf(v.w);
            u16 q0 = f2bf(v.x - bf2f(h0)), q1 = f2bf(v.y - bf2f(h1));
            u16 q2 = f2bf(v.z - bf2f(h2)), q3 = f2bf(v.w - bf2f(h3));
            u32 off = (u32)r * 256 + (((u32)c4 * 8) ^ (u32)((r & 7) << 4));
            *(uint2*)(xh + off) = make_uint2((u32)h0 | ((u32)h1 << 16), (u32)h2 | ((u32)h3 << 16));
            *(uint2*)(xl + off) = make_uint2((u32)q0 | ((u32)q1 << 16), (u32)q2 | ((u32)q3 << 16));
        }
    }
    __syncthreads();

    int w = t >> 6, l = t & 63;
    int lr = l & 15;
    int hi2 = l >> 4;
    int arow = w * 16 + lr;
    u32 aswz = (u32)((arow & 7) << 4);
    floatx4 acc[8];
#pragma unroll
    for (int nt = 0; nt < 8; ++nt) acc[nt] = (floatx4){0.f, 0.f, 0.f, 0.f};

#pragma unroll
    for (int kc = 0; kc < 4; ++kc) {
        u32 akoff = (u32)(kc * 64 + hi2 * 16);
        short8 ah = *(short8*)(xh + (u32)arow * 256 + (akoff ^ aswz));
        short8 al = *(short8*)(xl + (u32)arow * 256 + (akoff ^ aswz));
#pragma unroll
        for (int nt = 0; nt < 8; ++nt) {
            int brow = nt * 16 + lr;
            short8 bv = *(short8*)(wt + (u32)brow * 256 + (akoff ^ (u32)((brow & 7) << 4)));
            acc[nt] = __builtin_amdgcn_mfma_f32_16x16x32_bf16(ah, bv, acc[nt], 0, 0, 0);
            acc[nt] = __builtin_amdgcn_mfma_f32_16x16x32_bf16(al, bv, acc[nt], 0, 0, 0);
        }
    }

    int rbase = r0 + w * 16 + hi2 * 4;
#pragma unroll
    for (int q = 0; q < 4; ++q) {
        int grow = rbase + q;
        if (grow < NN) {
            float d = dis[grow];
#pragma unroll
            for (int nt = 0; nt < 8; ++nt) {
                g[(size_t)grow * 128 + nt * 16 + lr] = f2bf(d * acc[nt][q]);
            }
        }
    }
}

// out[i] = relu( dis[i]*(g[i] + sum g[src]) + b ) ; 4 nodes per wave, 16 lanes each, unroll 8.
__global__ __launch_bounds__(256) void k_aggr(const u32* __restrict__ g, const int* __restrict__ col,
                                              const int* __restrict__ start, const int* __restrict__ ecnt,
                                              const float* __restrict__ dis, const float* __restrict__ b,
                                              float* __restrict__ out) {
    int wv = (blockIdx.x * 256 + threadIdx.x) >> 6;
    int l = threadIdx.x & 63;
    int node = wv * 4 + (l >> 4);
    int sl = l & 15;
    if (node >= NN) return;
    const uint4* g4 = (const uint4*)g;
    int s = start[node], cnt = ecnt[node];

    uint4 sv = g4[(size_t)node * 16 + sl];   // self-loop term
    float2 t0 = bf2(sv.x), t1 = bf2(sv.y), t2 = bf2(sv.z), t3 = bf2(sv.w);
    float4 accA = make_float4(t0.x, t0.y, t1.x, t1.y);
    float4 accB = make_float4(t2.x, t2.y, t3.x, t3.y);

    int e = 0;
    if (cnt >= 8) {
        float4 ac2A = make_float4(0.f, 0.f, 0.f, 0.f);
        float4 ac2B = make_float4(0.f, 0.f, 0.f, 0.f);
        for (; e + 8 <= cnt; e += 8) {
            intx4 c0 = __builtin_nontemporal_load((const intx4*)&col[s + e]);
            intx4 c1 = __builtin_nontemporal_load((const intx4*)&col[s + e + 4]);
            uint4 a0 = g4[(size_t)c0.x * 16 + sl];
            uint4 a1 = g4[(size_t)c0.y * 16 + sl];
            uint4 a2 = g4[(size_t)c0.z * 16 + sl];
            uint4 a3 = g4[(size_t)c0.w * 16 + sl];
            uint4 a4 = g4[(size_t)c1.x * 16 + sl];
            uint4 a5 = g4[(size_t)c1.y * 16 + sl];
            uint4 a6 = g4[(size_t)c1.z * 16 + sl];
            uint4 a7 = g4[(size_t)c1.w * 16 + sl];
            acc8(accA, accB, a0);
            acc8(ac2A, ac2B, a1);
            acc8(accA, accB, a2);
            acc8(ac2A, ac2B, a3);
            acc8(accA, accB, a4);
            acc8(ac2A, ac2B, a5);
            acc8(accA, accB, a6);
            acc8(ac2A, ac2B, a7);
        }
        accA.x += ac2A.x; accA.y += ac2A.y; accA.z += ac2A.z; accA.w += ac2A.w;
        accB.x += ac2B.x; accB.y += ac2B.y; accB.z += ac2B.z; accB.w += ac2B.w;
    }
    if (e + 4 <= cnt) {
        intx4 c0 = __builtin_nontemporal_load((const intx4*)&col[s + e]);
        uint4 a0 = g4[(size_t)c0.x * 16 + sl];
        uint4 a1 = g4[(size_t)c0.y * 16 + sl];
        uint4 a2 = g4[(size_t)c0.z * 16 + sl];
        uint4 a3 = g4[(size_t)c0.w * 16 + sl];
        acc8(accA, accB, a0);
        acc8(accA, accB, a1);
        acc8(accA, accB, a2);
        acc8(accA, accB, a3);
        e += 4;
    }
    for (; e < cnt; ++e) {
        int sc = col[s + e];
        uint4 a = g4[(size_t)sc * 16 + sl];
        acc8(accA, accB, a);
    }

    float di = dis[node];
    float4 b0 = *(const float4*)&b[sl * 8];
    float4 b1 = *(const float4*)&b[sl * 8 + 4];
    fltx4 o0, o1;
    o0.x = fmaxf(fmaf(di, accA.x, b0.x), 0.f);
    o0.y = fmaxf(fmaf(di, accA.y, b0.y), 0.f);
    o0.z = fmaxf(fmaf(di, accA.z, b0.z), 0.f);
    o0.w = fmaxf(fmaf(di, accA.w, b0.w), 0.f);
    o1.x = fmaxf(fmaf(di, accB.x, b1.x), 0.f);
    o1.y = fmaxf(fmaf(di, accB.y, b1.y), 0.f);
    o1.z = fmaxf(fmaf(di, accB.z, b1.z), 0.f);
    o1.w = fmaxf(fmaf(di, accB.w, b1.w), 0.f);
    __builtin_nontemporal_store(o0, (fltx4*)&out[(size_t)node * 128 + sl * 8]);
    __builtin_nontemporal_store(o1, (fltx4*)&out[(size_t)node * 128 + sl * 8 + 4]);
}

extern "C" void kernel_launch(void* const* d_in, const int* in_sizes, int n_in,
                              void* d_out, int out_size, void* d_ws, size_t ws_size,
                              hipStream_t stream) {
    const float* x = (const float*)d_in[0];
    const int* ei = (const int*)d_in[1];
    const float* W = (const float*)d_in[2];
    const float* b = (const float*)d_in[3];
    float* out = (float*)d_out;
    const int* srcA = ei;        // edge_index[0] = message sources
    const int* dstA = ei + NE;   // edge_index[1] = aggregation targets

    char* ws = (char*)d_ws;
    size_t off = 0;
    auto take = [&](size_t bytes) -> char* {
        char* p = ws + off;
        off = (off + bytes + 255) & ~(size_t)255;
        return p;
    };
    u16*   g      = (u16*)  take((size_t)NN * 128 * 2);        // bf16 scaled features, 25.6 MB
    float* dis    = (float*)take((size_t)NN * 4);
    int*   ecnt   = (int*)  take((size_t)NN * 4);
    int*   startA = (int*)  take((size_t)NN * 4);
    int*   colA   = (int*)  take((size_t)NB * CAPC * 4);       // bucketed CSR cols, 11.2 MB
    int*   gcur   = (int*)  take(256 * 4);
    u16*   wtb    = (u16*)  take(128 * 128 * 2);               // pre-swizzled Wt bf16, 32KB

    u32* staging = (u32*)g;   // staging (9.6 MB) aliases g: g written only later by k_gemm

    k_prepW<<<64, 256, 0, stream>>>(W, wtb, gcur);
    k_binA <<<(NE + 8191) / 8192, 1024, 0, stream>>>(srcA, dstA, gcur, staging);
    k_passB<<<NB, 256, 0, stream>>>(staging, gcur, colA, startA, ecnt, dis);
    k_gemm <<<(NN + 63) / 64, 256, 0, stream>>>(x, wtb, dis, g);
    k_aggr <<<(NN + 15) / 16, 256, 0, stream>>>((const u32*)g, colA, startA, ecnt, dis, b, out);
}